// Round 3
// baseline (444.408 us; speedup 1.0000x reference)
//
#include <hip/hip_runtime.h>
#include <hip/hip_bf16.h>
#include <stdint.h>

// Problem constants
#define S_LEN 2048
#define BATCH 32
#define MROWS (S_LEN*BATCH)   // 65536 GEMM rows, K=N=1024

typedef __attribute__((ext_vector_type(8))) short bf16x8;
typedef __attribute__((ext_vector_type(4))) float f32x4;
typedef unsigned short ushort_t;

__device__ inline unsigned int pk2bf(float a, float b) {
  float2 t; t.x = a; t.y = b;
  __hip_bfloat162 h = __float22bfloat162_rn(t);
  union { __hip_bfloat162 h; unsigned int u; } c; c.h = h;
  return c.u;
}

__device__ inline float bflo(unsigned int u) { return __uint_as_float(u << 16); }
__device__ inline float bfhi(unsigned int u) { return __uint_as_float(u & 0xffff0000u); }

__device__ inline void gload_lds16(const void* g, void* l) {
  __builtin_amdgcn_global_load_lds(
      (const __attribute__((address_space(1))) unsigned int*)g,
      (__attribute__((address_space(3))) unsigned int*)l, 16, 0, 0);
}

__device__ inline float fast_tanh(float x) {
  float e = __expf(2.0f * x);
  return 1.0f - 2.0f / (e + 1.0f);
}

// ---------------------------------------------------------------------------
// prep_conv: blocks 0..2047 convert enc fp32->bf16 (streaming);
//            blocks 2048..2111 convert Wc -> bf16;
//            blocks 2112..2143 compute wsum[b][n] = sum_d dec[b][d]*Wb[n][d]
// ---------------------------------------------------------------------------
__global__ __launch_bounds__(256) void prep_conv_kernel(
    const float* __restrict__ dec, const float* __restrict__ Wb,
    const float* __restrict__ Wc, const float* __restrict__ enc,
    ushort_t* __restrict__ encBf, ushort_t* __restrict__ WcBf,
    float* __restrict__ wsum)
{
  const int t = threadIdx.x;
  const int bid = blockIdx.x;
  if (bid < 2048) {
    const size_t base = (size_t)bid * 4096;     // 8M chunks of 8 elems total
    for (int it = 0; it < 16; ++it) {
      const size_t i = base + it * 256 + t;
      const float4* p = (const float4*)enc + i * 2;
      float4 a = p[0], b = p[1];
      uint4 w;
      w.x = pk2bf(a.x, a.y); w.y = pk2bf(a.z, a.w);
      w.z = pk2bf(b.x, b.y); w.w = pk2bf(b.z, b.w);
      ((uint4*)encBf)[i] = w;
    }
  } else if (bid < 2112) {
    const int base = (bid - 2048) * 16384;
    for (int i = 0; i < 16; ++i) {
      int idx = base + i * 1024 + t * 4;
      float4 v = *(const float4*)(Wc + idx);
      uint2 w; w.x = pk2bf(v.x, v.y); w.y = pk2bf(v.z, v.w);
      *(uint2*)(WcBf + idx) = w;
    }
  } else {
    const int j = bid - 2112;                   // n-slice [j*32, j*32+32)
    __shared__ float sdec[32][65];
    __shared__ float swb[32][65];
    const int b = t & 31, nl = t >> 5;
    float acc0 = 0.f, acc1 = 0.f, acc2 = 0.f, acc3 = 0.f;
    for (int c = 0; c < 16; ++c) {
      __syncthreads();
      for (int idx = t; idx < 2048; idx += 256) {
        int rr = idx >> 6, dd = idx & 63;
        sdec[rr][dd] = dec[rr * 1024 + c * 64 + dd];
        swb[rr][dd]  = Wb[(size_t)(j * 32 + rr) * 1024 + c * 64 + dd];
      }
      __syncthreads();
      #pragma unroll 8
      for (int dd = 0; dd < 64; ++dd) {
        float dv = sdec[b][dd];
        acc0 += dv * swb[nl][dd];
        acc1 += dv * swb[nl + 8][dd];
        acc2 += dv * swb[nl + 16][dd];
        acc3 += dv * swb[nl + 24][dd];
      }
    }
    wsum[b * 1024 + j * 32 + nl]      = acc0;
    wsum[b * 1024 + j * 32 + nl + 8]  = acc1;
    wsum[b * 1024 + j * 32 + nl + 16] = acc2;
    wsum[b * 1024 + j * 32 + nl + 24] = acc3;
  }
}

// ---------------------------------------------------------------------------
// score: BM=128 x BN=256 tile, BK=64, 8 waves (2M x 4N), per-wave 64x64.
// 2-phase double-buffered LDS: stage(step+1) issued BEFORE compute(step),
// one barrier per K-step (loads in flight across the MFMA phase).
// nb loop: 4 panels of 256 cols; epilogue folds tanh(.+wsum).Wa into score,
// then exp + per-block partial sums (softmax fused, no max needed: |score|~1).
// XOR chunk-swizzle (c ^ (r&7)) on both stage-source and frag-read: 0 conflicts.
// ---------------------------------------------------------------------------
__global__ __launch_bounds__(512, 2) void score_kernel(
    const ushort_t* __restrict__ encBf, const ushort_t* __restrict__ WcBf,
    const float* __restrict__ wsum, const float* __restrict__ Wa,
    float* __restrict__ expS, float* __restrict__ gSumP)
{
  __shared__ ushort_t Ab[2][128][64];   // 32 KB (2 x 16 KB)
  __shared__ ushort_t Bb[2][256][64];   // 64 KB (2 x 32 KB)
  __shared__ float scorep[128];

  const int tid = threadIdx.x;
  const int lane = tid & 63;
  const int l15 = lane & 15, q = lane >> 4;
  const int wid = tid >> 6;
  const int wr = wid >> 2, wc = wid & 3;        // 2M x 4N wave grid
  const size_t rowBase = (size_t)blockIdx.x * 128;

  if (tid < 128) scorep[tid] = 0.f;

  // A staging: 1024 slots of 16B, 2/thread (slots tid, tid+512)
  const int ar0 = tid >> 3, ac0 = tid & 7;
  const int aSwz = (ac0 ^ (ar0 & 7)) * 8;       // (r+64)&7 == r&7
  const ushort_t* aS0 = encBf + (rowBase + ar0) * 1024 + aSwz;
  const ushort_t* aS1 = aS0 + (size_t)64 * 1024;
  const int aD0 = tid * 8, aD1 = (tid + 512) * 8;

  // B staging: 2048 slots, 4/thread (slots k*512+tid)
  int bSrcOff[4], bD[4];
  #pragma unroll
  for (int k = 0; k < 4; ++k) {
    const int s = k * 512 + tid;
    const int r = s >> 3, c = s & 7;
    bSrcOff[k] = r * 1024 + ((c ^ (r & 7)) * 8);
    bD[k] = s * 8;
  }

  f32x4 acc[4][4];
  #pragma unroll
  for (int m = 0; m < 4; ++m)
    #pragma unroll
    for (int n = 0; n < 4; ++n) { f32x4 z = {0.f,0.f,0.f,0.f}; acc[m][n] = z; }

  // prologue: stage step 0 into buf 0
  {
    ushort_t* ab = &Ab[0][0][0];
    ushort_t* bb = &Bb[0][0][0];
    gload_lds16(aS0, ab + aD0);
    gload_lds16(aS1, ab + aD1);
    #pragma unroll
    for (int k = 0; k < 4; ++k)
      gload_lds16(WcBf + bSrcOff[k], bb + bD[k]);
  }
  __syncthreads();   // implicit vmcnt(0) drain

  for (int s = 0; s < 64; ++s) {               // (nb, kt) flattened: nb=s>>4
    const int cur = s & 1;
    if (s < 63) {                              // stage step s+1 into buf cur^1
      const int s2 = s + 1;
      const int ko = (s2 & 15) * 64;
      ushort_t* ab = &Ab[cur ^ 1][0][0];
      ushort_t* bb = &Bb[cur ^ 1][0][0];
      gload_lds16(aS0 + ko, ab + aD0);
      gload_lds16(aS1 + ko, ab + aD1);
      const ushort_t* bsrc = WcBf + (size_t)(s2 >> 4) * 262144 + ko;
      #pragma unroll
      for (int k = 0; k < 4; ++k)
        gload_lds16(bsrc + bSrcOff[k], bb + bD[k]);
    }

    // compute from buf cur
    #pragma unroll
    for (int kk = 0; kk < 2; ++kk) {
      bf16x8 af[4], bv[4];
      #pragma unroll
      for (int m = 0; m < 4; ++m) {
        const int row = wr * 64 + m * 16 + l15;
        const int ch = (kk * 4 + q) ^ (row & 7);
        af[m] = *(const bf16x8*)&Ab[cur][row][ch * 8];
      }
      #pragma unroll
      for (int n = 0; n < 4; ++n) {
        const int row = wc * 64 + n * 16 + l15;
        const int ch = (kk * 4 + q) ^ (row & 7);
        bv[n] = *(const bf16x8*)&Bb[cur][row][ch * 8];
      }
      #pragma unroll
      for (int m = 0; m < 4; ++m)
        #pragma unroll
        for (int n = 0; n < 4; ++n)
          acc[m][n] = __builtin_amdgcn_mfma_f32_16x16x32_bf16(
              af[m], bv[n], acc[m][n], 0, 0, 0);
    }

    if ((s & 15) == 15) {                      // epilogue for panel nb
      const int nb = s >> 4;
      #pragma unroll
      for (int m = 0; m < 4; ++m) {
        #pragma unroll
        for (int i = 0; i < 4; ++i) {
          const int rowl = wr * 64 + m * 16 + q * 4 + i;
          const int bb2 = rowl & 31;           // global row %32 == rowl%32
          float v = 0.f;
          #pragma unroll
          for (int n = 0; n < 4; ++n) {
            const int col = nb * 256 + wc * 64 + n * 16 + l15;
            float x = acc[m][n][i] + wsum[bb2 * 1024 + col];
            v += fast_tanh(x) * Wa[col];
          }
          v += __shfl_xor(v, 1); v += __shfl_xor(v, 2);
          v += __shfl_xor(v, 4); v += __shfl_xor(v, 8);
          if (l15 == 0) atomicAdd(&scorep[rowl], v);
        }
      }
      #pragma unroll
      for (int m = 0; m < 4; ++m)
        #pragma unroll
        for (int n = 0; n < 4; ++n) { f32x4 z = {0.f,0.f,0.f,0.f}; acc[m][n] = z; }
    }
    __syncthreads();   // drains staged loads of step s+1; flips buffers
  }

  // fused softmax numerator: e = exp(score) (scores O(1), no max needed)
  if (tid < 128) {
    float e = __expf(scorep[tid]);
    expS[rowBase + tid] = e;
    scorep[tid] = e;
  }
  __syncthreads();
  if (tid < 32) {   // per-block partial sum per batch col: rows tid,+32,+64,+96
    float v = scorep[tid] + scorep[tid + 32] + scorep[tid + 64] + scorep[tid + 96];
    gSumP[tid * 512 + blockIdx.x] = v;          // layout [32][512]
  }
}

// ---------------------------------------------------------------------------
// ctx: block (b, sc): reduce gSumP[b][.] -> 1/sum, then
// out[b][e] += inv * sum_{s in chunk} expS[s,b] * encBf[s,b,e]  (atomicAdd)
// ---------------------------------------------------------------------------
__global__ __launch_bounds__(256) void ctx_kernel(
    const ushort_t* __restrict__ encBf, const float* __restrict__ expS,
    const float* __restrict__ gSumP, float* __restrict__ out)
{
  const int b = blockIdx.x & 31, sc = blockIdx.x >> 5;
  const int t = threadIdx.x;
  __shared__ float red[256];
  red[t] = gSumP[b * 512 + t] + gSumP[b * 512 + 256 + t];
  __syncthreads();
  #pragma unroll
  for (int o = 128; o > 0; o >>= 1) {
    if (t < o) red[t] += red[t + o];
    __syncthreads();
  }
  const float inv = 1.0f / red[0];

  float a0 = 0.f, a1 = 0.f, a2 = 0.f, a3 = 0.f;
  const int e0 = t * 4;
  #pragma unroll 4
  for (int si = 0; si < 128; ++si) {
    const int s = sc * 128 + si;
    const float a = expS[s * 32 + b];
    uint2 w = *(const uint2*)(encBf + ((size_t)s * 32 + b) * 1024 + e0);
    a0 += a * bflo(w.x); a1 += a * bfhi(w.x);
    a2 += a * bflo(w.y); a3 += a * bfhi(w.y);
  }
  float* op = out + b * 1024 + e0;
  atomicAdd(op + 0, a0 * inv); atomicAdd(op + 1, a1 * inv);
  atomicAdd(op + 2, a2 * inv); atomicAdd(op + 3, a3 * inv);
}

// ---------------------------------------------------------------------------
extern "C" void kernel_launch(void* const* d_in, const int* in_sizes, int n_in,
                              void* d_out, int out_size, void* d_ws, size_t ws_size,
                              hipStream_t stream) {
  const float* dec = (const float*)d_in[0];
  const float* enc = (const float*)d_in[1];
  const float* Wb  = (const float*)d_in[2];
  const float* Wc  = (const float*)d_in[3];
  const float* Wa  = (const float*)d_in[4];
  float* out = (float*)d_out;
  (void)in_sizes; (void)n_in; (void)ws_size;

  char* ws = (char*)d_ws;
  ushort_t* encBf = (ushort_t*)ws;                               // 128 MB
  ushort_t* WcBf  = (ushort_t*)(ws + 134217728);                 // 2 MB
  float*    wsum  = (float*)(ws + 134217728 + 2097152);          // 128 KB
  float*    expS  = (float*)(ws + 134217728 + 2097152 + 131072); // 256 KB
  float*    gSumP = (float*)(ws + 134217728 + 2097152 + 131072 + 262144); // 64 KB

  hipMemsetAsync(out, 0, (size_t)out_size * sizeof(float), stream);
  prep_conv_kernel<<<2144, 256, 0, stream>>>(dec, Wb, Wc, enc, encBf, WcBf, wsum);
  score_kernel<<<512, 512, 0, stream>>>(encBf, WcBf, wsum, Wa, expS, gSumP);
  ctx_kernel<<<512, 256, 0, stream>>>(encBf, expS, gSumP, out);
}

// Round 4
// 435.615 us; speedup vs baseline: 1.0202x; 1.0202x over previous
//
#include <hip/hip_runtime.h>
#include <hip/hip_bf16.h>
#include <stdint.h>

// Problem constants
#define S_LEN 2048
#define BATCH 32
#define MROWS (S_LEN*BATCH)   // 65536 GEMM rows, K=N=1024

typedef __attribute__((ext_vector_type(8))) short bf16x8;
typedef __attribute__((ext_vector_type(4))) float f32x4;
typedef unsigned short ushort_t;

__device__ inline unsigned int pk2bf(float a, float b) {
  float2 t; t.x = a; t.y = b;
  __hip_bfloat162 h = __float22bfloat162_rn(t);
  union { __hip_bfloat162 h; unsigned int u; } c; c.h = h;
  return c.u;
}

__device__ inline float bflo(unsigned int u) { return __uint_as_float(u << 16); }
__device__ inline float bfhi(unsigned int u) { return __uint_as_float(u & 0xffff0000u); }

__device__ inline void gload_lds16(const void* g, void* l) {
  __builtin_amdgcn_global_load_lds(
      (const __attribute__((address_space(1))) unsigned int*)g,
      (__attribute__((address_space(3))) unsigned int*)l, 16, 0, 0);
}

__device__ inline float fast_tanh(float x) {
  float e = __expf(2.0f * x);
  return 1.0f - 2.0f / (e + 1.0f);
}

// ---------------------------------------------------------------------------
// prep_conv: blocks 0..2047 convert enc fp32->bf16 (streaming);
//            blocks 2048..2111 convert Wc -> bf16;
//            blocks 2112..2143 compute wsum[b][n] = sum_d dec[b][d]*Wb[n][d]
// ---------------------------------------------------------------------------
__global__ __launch_bounds__(256) void prep_conv_kernel(
    const float* __restrict__ dec, const float* __restrict__ Wb,
    const float* __restrict__ Wc, const float* __restrict__ enc,
    ushort_t* __restrict__ encBf, ushort_t* __restrict__ WcBf,
    float* __restrict__ wsum)
{
  const int t = threadIdx.x;
  const int bid = blockIdx.x;
  if (bid < 2048) {
    const size_t base = (size_t)bid * 4096;
    for (int it = 0; it < 16; ++it) {
      const size_t i = base + it * 256 + t;
      const float4* p = (const float4*)enc + i * 2;
      float4 a = p[0], b = p[1];
      uint4 w;
      w.x = pk2bf(a.x, a.y); w.y = pk2bf(a.z, a.w);
      w.z = pk2bf(b.x, b.y); w.w = pk2bf(b.z, b.w);
      ((uint4*)encBf)[i] = w;
    }
  } else if (bid < 2112) {
    const int base = (bid - 2048) * 16384;
    for (int i = 0; i < 16; ++i) {
      int idx = base + i * 1024 + t * 4;
      float4 v = *(const float4*)(Wc + idx);
      uint2 w; w.x = pk2bf(v.x, v.y); w.y = pk2bf(v.z, v.w);
      *(uint2*)(WcBf + idx) = w;
    }
  } else {
    const int j = bid - 2112;                   // n-slice [j*32, j*32+32)
    __shared__ float sdec[32][65];
    __shared__ float swb[32][65];
    const int b = t & 31, nl = t >> 5;
    float acc0 = 0.f, acc1 = 0.f, acc2 = 0.f, acc3 = 0.f;
    for (int c = 0; c < 16; ++c) {
      __syncthreads();
      for (int idx = t; idx < 2048; idx += 256) {
        int rr = idx >> 6, dd = idx & 63;
        sdec[rr][dd] = dec[rr * 1024 + c * 64 + dd];
        swb[rr][dd]  = Wb[(size_t)(j * 32 + rr) * 1024 + c * 64 + dd];
      }
      __syncthreads();
      #pragma unroll 8
      for (int dd = 0; dd < 64; ++dd) {
        float dv = sdec[b][dd];
        acc0 += dv * swb[nl][dd];
        acc1 += dv * swb[nl + 8][dd];
        acc2 += dv * swb[nl + 16][dd];
        acc3 += dv * swb[nl + 24][dd];
      }
    }
    wsum[b * 1024 + j * 32 + nl]      = acc0;
    wsum[b * 1024 + j * 32 + nl + 8]  = acc1;
    wsum[b * 1024 + j * 32 + nl + 16] = acc2;
    wsum[b * 1024 + j * 32 + nl + 24] = acc3;
  }
}

// ---------------------------------------------------------------------------
// score: BM=128, BN=256, BK=64, 8 waves (2M x 4N), wave tile 64x64.
// Counted-vmcnt pipeline: A (HBM) depth-4 buffers, prefetch distance 3;
// B (L2-resident, 2MB) depth-2, distance 1. Two raw s_barriers per K-step,
// vmcnt(8) — never drained to 0 in the main loop. XOR-8 chunk swizzle
// (src-side pre-swizzle + swizzled frag read) -> 0 bank conflicts.
// Epilogue per 256-col panel folds tanh(.+wsum).Wa into score rows; final
// exp + per-block partial sums (softmax fused; scores are O(1), no max).
// ---------------------------------------------------------------------------
__global__ __launch_bounds__(512, 1) void score_kernel(
    const ushort_t* __restrict__ encBf, const ushort_t* __restrict__ WcBf,
    const float* __restrict__ wsum, const float* __restrict__ Wa,
    float* __restrict__ expS, float* __restrict__ gSumP)
{
  __shared__ ushort_t Ab[4][128][64];   // 64 KB, 4 buffers
  __shared__ ushort_t Bb[2][256][64];   // 64 KB, 2 buffers
  __shared__ float scorep[128];

  const int tid = threadIdx.x;
  const int lane = tid & 63;
  const int l15 = lane & 15, q = lane >> 4;
  const int r7 = l15 & 7;
  const int wid = tid >> 6;
  const int wr = wid >> 2, wc = wid & 3;        // 2M x 4N waves
  const size_t rowBase = (size_t)blockIdx.x * 128;

  if (tid < 128) scorep[tid] = 0.f;

  ushort_t* const aB = &Ab[0][0][0];
  ushort_t* const bB = &Bb[0][0][0];

  // A staging: 1024 slots of 16B per buffer, 2/thread (tid, tid+512)
  const int ar0 = tid >> 3, ac0 = tid & 7;
  const ushort_t* aS0 = encBf + (rowBase + ar0) * 1024 + ((ac0 ^ (ar0 & 7)) * 8);
  const ushort_t* aS1 = aS0 + (size_t)64 * 1024;   // rows +64: same &7 -> same swz
  const int aD0 = tid * 8, aD1 = (tid + 512) * 8;

  // B staging: 2048 slots per buffer, 4/thread
  int bOff[4], bDst[4];
  #pragma unroll
  for (int k = 0; k < 4; ++k) {
    const int s = k * 512 + tid;
    const int r = s >> 3, c = s & 7;
    bOff[k] = r * 1024 + ((c ^ (r & 7)) * 8);
    bDst[k] = s * 8;
  }

  // frag read offsets (ushort units); (row&7) == (l15&7) for all frags
  int aRow[4], bRow[4];
  #pragma unroll
  for (int m = 0; m < 4; ++m) aRow[m] = (wr * 64 + m * 16 + l15) * 64;
  #pragma unroll
  for (int n = 0; n < 4; ++n) bRow[n] = (wc * 64 + n * 16 + l15) * 64;
  const int ch0 = (q ^ r7) * 8;
  const int ch1 = ((4 + q) ^ r7) * 8;

  f32x4 acc[4][4];
  #pragma unroll
  for (int m = 0; m < 4; ++m)
    #pragma unroll
    for (int n = 0; n < 4; ++n) { f32x4 z = {0.f,0.f,0.f,0.f}; acc[m][n] = z; }

  // prologue (issue order matters for FIFO vmcnt): A0, B0, A1, A2
  gload_lds16(aS0, aB + aD0);
  gload_lds16(aS1, aB + aD1);
  #pragma unroll
  for (int k = 0; k < 4; ++k)
    gload_lds16(WcBf + bOff[k], bB + bDst[k]);
  gload_lds16(aS0 + 64,  aB + 8192 + aD0);
  gload_lds16(aS1 + 64,  aB + 8192 + aD1);
  gload_lds16(aS0 + 128, aB + 16384 + aD0);
  gload_lds16(aS1 + 128, aB + 16384 + aD1);

  for (int t = 0; t < 64; ++t) {
    // stage B(t+1) [distance 1], then A(t+3) [distance 3]
    {
      const int jb = (t + 1) & 63;
      const ushort_t* bsrc = WcBf + (size_t)(jb >> 4) * 262144 + (jb & 15) * 64;
      ushort_t* bd = bB + ((t + 1) & 1) * 16384;
      #pragma unroll
      for (int k = 0; k < 4; ++k)
        gload_lds16(bsrc + bOff[k], bd + bDst[k]);
      const int ja = t + 3;
      const int ko = (ja & 15) * 64;
      ushort_t* ad = aB + (ja & 3) * 8192;
      gload_lds16(aS0 + ko, ad + aD0);
      gload_lds16(aS1 + ko, ad + aD1);
    }

    asm volatile("s_waitcnt vmcnt(8)" ::: "memory");
    __builtin_amdgcn_s_barrier();

    const ushort_t* ab = aB + (t & 3) * 8192;
    const ushort_t* bb = bB + (t & 1) * 16384;
    #pragma unroll
    for (int kk = 0; kk < 2; ++kk) {
      const int cho = kk ? ch1 : ch0;
      bf16x8 af[4], bv[4];
      #pragma unroll
      for (int m = 0; m < 4; ++m) af[m] = *(const bf16x8*)(ab + aRow[m] + cho);
      #pragma unroll
      for (int n = 0; n < 4; ++n) bv[n] = *(const bf16x8*)(bb + bRow[n] + cho);
      #pragma unroll
      for (int m = 0; m < 4; ++m)
        #pragma unroll
        for (int n = 0; n < 4; ++n)
          acc[m][n] = __builtin_amdgcn_mfma_f32_16x16x32_bf16(
              af[m], bv[n], acc[m][n], 0, 0, 0);
    }

    if ((t & 15) == 15) {                       // panel epilogue
      const int nb = t >> 4;
      #pragma unroll
      for (int m = 0; m < 4; ++m) {
        #pragma unroll
        for (int i = 0; i < 4; ++i) {
          const int rowl = wr * 64 + m * 16 + q * 4 + i;
          const int bb2 = rowl & 31;            // global row %32 == rowl%32
          float v = 0.f;
          #pragma unroll
          for (int n = 0; n < 4; ++n) {
            const int col = nb * 256 + wc * 64 + n * 16 + l15;
            float x = acc[m][n][i] + wsum[bb2 * 1024 + col];
            v += fast_tanh(x) * Wa[col];
          }
          v += __shfl_xor(v, 1); v += __shfl_xor(v, 2);
          v += __shfl_xor(v, 4); v += __shfl_xor(v, 8);
          if (l15 == 0) atomicAdd(&scorep[rowl], v);
        }
      }
      #pragma unroll
      for (int m = 0; m < 4; ++m)
        #pragma unroll
        for (int n = 0; n < 4; ++n) { f32x4 z = {0.f,0.f,0.f,0.f}; acc[m][n] = z; }
    }
    __builtin_amdgcn_s_barrier();   // protect buffers from next iter's stages
  }

  __syncthreads();                  // full drain before scorep consumption
  if (tid < 128) {
    float e = __expf(scorep[tid]);  // scores O(1): exp w/o max is safe
    expS[rowBase + tid] = e;
    scorep[tid] = e;
  }
  __syncthreads();
  if (tid < 32) {
    float v = scorep[tid] + scorep[tid + 32] + scorep[tid + 64] + scorep[tid + 96];
    gSumP[tid * 512 + blockIdx.x] = v;          // layout [32][512]
  }
}

// ---------------------------------------------------------------------------
// ctx partials: block (b, sc): partial[sc][b][e] = sum_{s in chunk} expS*encBf
// ---------------------------------------------------------------------------
__global__ __launch_bounds__(256) void ctx_partial_kernel(
    const ushort_t* __restrict__ encBf, const float* __restrict__ expS,
    float* __restrict__ partial)
{
  const int b = blockIdx.x & 31, sc = blockIdx.x >> 5;
  const int t = threadIdx.x;
  float a0 = 0.f, a1 = 0.f, a2 = 0.f, a3 = 0.f;
  const int e0 = t * 4;
  #pragma unroll 4
  for (int si = 0; si < 128; ++si) {
    const int s = sc * 128 + si;
    const float a = expS[s * 32 + b];
    uint2 w = *(const uint2*)(encBf + ((size_t)s * 32 + b) * 1024 + e0);
    a0 += a * bflo(w.x); a1 += a * bfhi(w.x);
    a2 += a * bflo(w.y); a3 += a * bfhi(w.y);
  }
  *(float4*)(partial + ((size_t)(sc * 32 + b)) * 1024 + e0) =
      make_float4(a0, a1, a2, a3);
}

// ---------------------------------------------------------------------------
// ctx reduce: sum 16 partials, scale by 1/sum(exp) from gSumP, write out
// ---------------------------------------------------------------------------
__global__ __launch_bounds__(256) void ctx_reduce_kernel(
    const float* __restrict__ partial, const float* __restrict__ gSumP,
    float* __restrict__ out)
{
  const int b = blockIdx.x, t = threadIdx.x;
  __shared__ float red[256];
  red[t] = gSumP[b * 512 + t] + gSumP[b * 512 + 256 + t];
  __syncthreads();
  #pragma unroll
  for (int o = 128; o > 0; o >>= 1) {
    if (t < o) red[t] += red[t + o];
    __syncthreads();
  }
  const float inv = 1.0f / red[0];

  float4 acc = make_float4(0.f, 0.f, 0.f, 0.f);
  #pragma unroll
  for (int p = 0; p < 16; ++p) {
    float4 v = *(const float4*)(partial + ((size_t)(p * 32 + b)) * 1024 + t * 4);
    acc.x += v.x; acc.y += v.y; acc.z += v.z; acc.w += v.w;
  }
  acc.x *= inv; acc.y *= inv; acc.z *= inv; acc.w *= inv;
  *(float4*)(out + (size_t)b * 1024 + t * 4) = acc;
}

// ---------------------------------------------------------------------------
extern "C" void kernel_launch(void* const* d_in, const int* in_sizes, int n_in,
                              void* d_out, int out_size, void* d_ws, size_t ws_size,
                              hipStream_t stream) {
  const float* dec = (const float*)d_in[0];
  const float* enc = (const float*)d_in[1];
  const float* Wb  = (const float*)d_in[2];
  const float* Wc  = (const float*)d_in[3];
  const float* Wa  = (const float*)d_in[4];
  float* out = (float*)d_out;
  (void)in_sizes; (void)n_in; (void)ws_size; (void)out_size;

  char* ws = (char*)d_ws;
  ushort_t* encBf = (ushort_t*)ws;                                         // 128 MB
  ushort_t* WcBf  = (ushort_t*)(ws + 134217728);                           // 2 MB
  float*    wsum  = (float*)(ws + 134217728 + 2097152);                    // 128 KB
  float*    expS  = (float*)(ws + 134217728 + 2097152 + 131072);           // 256 KB
  float*    gSumP = (float*)(ws + 134217728 + 2097152 + 131072 + 262144);  // 64 KB
  float*  partial = (float*)(ws + 134217728 + 2097152 + 131072 + 262144 + 65536); // 2 MB

  prep_conv_kernel<<<2144, 256, 0, stream>>>(dec, Wb, Wc, enc, encBf, WcBf, wsum);
  score_kernel<<<512, 512, 0, stream>>>(encBf, WcBf, wsum, Wa, expS, gSumP);
  ctx_partial_kernel<<<512, 256, 0, stream>>>(encBf, expS, partial);
  ctx_reduce_kernel<<<32, 256, 0, stream>>>(partial, gSumP, out);
}

// Round 5
// 383.637 us; speedup vs baseline: 1.1584x; 1.1355x over previous
//
#include <hip/hip_runtime.h>
#include <hip/hip_bf16.h>
#include <stdint.h>

// Problem constants
#define S_LEN 2048
#define BATCH 32
#define MROWS (S_LEN*BATCH)   // 65536 GEMM rows, K=N=1024

typedef __attribute__((ext_vector_type(8))) short bf16x8;
typedef __attribute__((ext_vector_type(4))) float f32x4;
typedef unsigned short ushort_t;

__device__ inline unsigned int pk2bf(float a, float b) {
  float2 t; t.x = a; t.y = b;
  __hip_bfloat162 h = __float22bfloat162_rn(t);
  union { __hip_bfloat162 h; unsigned int u; } c; c.h = h;
  return c.u;
}

__device__ inline float bflo(unsigned int u) { return __uint_as_float(u << 16); }
__device__ inline float bfhi(unsigned int u) { return __uint_as_float(u & 0xffff0000u); }

__device__ inline void gload_lds16(const void* g, void* l) {
  __builtin_amdgcn_global_load_lds(
      (const __attribute__((address_space(1))) unsigned int*)g,
      (__attribute__((address_space(3))) unsigned int*)l, 16, 0, 0);
}

__device__ inline float fast_tanh(float x) {
  float e = __expf(2.0f * x);
  return 1.0f - 2.0f / (e + 1.0f);
}

// ---------------------------------------------------------------------------
// prep_conv: blocks 0..2047 convert enc fp32->bf16 (streaming);
//            blocks 2048..2111 convert Wc -> bf16;
//            blocks 2112..2143 compute wsum[b][n] = sum_d dec[b][d]*Wb[n][d]
// ---------------------------------------------------------------------------
__global__ __launch_bounds__(256) void prep_conv_kernel(
    const float* __restrict__ dec, const float* __restrict__ Wb,
    const float* __restrict__ Wc, const float* __restrict__ enc,
    ushort_t* __restrict__ encBf, ushort_t* __restrict__ WcBf,
    float* __restrict__ wsum)
{
  const int t = threadIdx.x;
  const int bid = blockIdx.x;
  if (bid < 2048) {
    const size_t base = (size_t)bid * 4096;
    for (int it = 0; it < 16; ++it) {
      const size_t i = base + it * 256 + t;
      const float4* p = (const float4*)enc + i * 2;
      float4 a = p[0], b = p[1];
      uint4 w;
      w.x = pk2bf(a.x, a.y); w.y = pk2bf(a.z, a.w);
      w.z = pk2bf(b.x, b.y); w.w = pk2bf(b.z, b.w);
      ((uint4*)encBf)[i] = w;
    }
  } else if (bid < 2112) {
    const int base = (bid - 2048) * 16384;
    for (int i = 0; i < 16; ++i) {
      int idx = base + i * 1024 + t * 4;
      float4 v = *(const float4*)(Wc + idx);
      uint2 w; w.x = pk2bf(v.x, v.y); w.y = pk2bf(v.z, v.w);
      *(uint2*)(WcBf + idx) = w;
    }
  } else {
    const int j = bid - 2112;                   // n-slice [j*32, j*32+32)
    __shared__ float sdec[32][65];
    __shared__ float swb[32][65];
    const int b = t & 31, nl = t >> 5;
    float acc0 = 0.f, acc1 = 0.f, acc2 = 0.f, acc3 = 0.f;
    for (int c = 0; c < 16; ++c) {
      __syncthreads();
      for (int idx = t; idx < 2048; idx += 256) {
        int rr = idx >> 6, dd = idx & 63;
        sdec[rr][dd] = dec[rr * 1024 + c * 64 + dd];
        swb[rr][dd]  = Wb[(size_t)(j * 32 + rr) * 1024 + c * 64 + dd];
      }
      __syncthreads();
      #pragma unroll 8
      for (int dd = 0; dd < 64; ++dd) {
        float dv = sdec[b][dd];
        acc0 += dv * swb[nl][dd];
        acc1 += dv * swb[nl + 8][dd];
        acc2 += dv * swb[nl + 16][dd];
        acc3 += dv * swb[nl + 24][dd];
      }
    }
    wsum[b * 1024 + j * 32 + nl]      = acc0;
    wsum[b * 1024 + j * 32 + nl + 8]  = acc1;
    wsum[b * 1024 + j * 32 + nl + 16] = acc2;
    wsum[b * 1024 + j * 32 + nl + 24] = acc3;
  }
}

// ---------------------------------------------------------------------------
// score (m97 structure): BM=128, BN=128, BK=64, 4 waves (2x2), wave 64x64.
// Single-buffered 32KB LDS, 2 barriers/K-step, 32 MFMA between barriers;
// latency hidden by 4 blocks/CU (launch_bounds(256,4)), not src pipelining.
// XOR-8 chunk swizzle on both stage source and frag read -> 0 bank conflicts.
// XCD-aware bid decode: the 8 blocks sharing an A-panel (same m, n=0..7)
// differ only in bid bits 4..6 -> identical bid%8 -> same XCD -> A-panel
// fetched ~once per XCD into its private L2.
// Epilogue: scoreP8[row][n] = sum_col tanh(acc + wsum) * Wa  (disjoint slices,
// no global atomics, deterministic).
// ---------------------------------------------------------------------------
__global__ __launch_bounds__(256, 4) void score_kernel(
    const ushort_t* __restrict__ encBf, const ushort_t* __restrict__ WcBf,
    const float* __restrict__ wsum, const float* __restrict__ Wa,
    float* __restrict__ scoreP8)
{
  __shared__ ushort_t Ab[128][64];   // 16 KB
  __shared__ ushort_t Bb[128][64];   // 16 KB
  __shared__ float scorep[128];

  const int tid = threadIdx.x;
  const int lane = tid & 63;
  const int l15 = lane & 15, q = lane >> 4;
  const int r7 = l15 & 7;
  const int wid = tid >> 6;
  const int wr = wid >> 1, wc = wid & 1;        // 2M x 2N waves
  // bid decode: mi (0..15) fastest, n (0..7), mg (0..31)
  const int bid = blockIdx.x;
  const int mi = bid & 15, nblk = (bid >> 4) & 7, mg = bid >> 7;
  const size_t rowBase = (size_t)(mg * 16 + mi) * 128;

  if (tid < 128) scorep[tid] = 0.f;

  // staging: 1024 slots of 16B per tile, 4 per thread (s = k*256+tid)
  int aOff[4], bOff[4], dOff[4];
  #pragma unroll
  for (int k = 0; k < 4; ++k) {
    const int s = k * 256 + tid;
    const int r = s >> 3, c = s & 7;
    const int swz = (c ^ (r & 7)) * 8;
    aOff[k] = (int)(r * 1024 + swz);
    bOff[k] = (int)((nblk * 128 + r) * 1024 + swz);
    dOff[k] = s * 8;
  }
  const ushort_t* aBase = encBf + rowBase * 1024;
  ushort_t* const aL = &Ab[0][0];
  ushort_t* const bL = &Bb[0][0];

  // frag addressing: row&7 == l15&7 for all frags (offsets are multiples of 8)
  int aRow[4], bRow[4];
  #pragma unroll
  for (int m = 0; m < 4; ++m) aRow[m] = (wr * 64 + m * 16 + l15) * 64;
  #pragma unroll
  for (int n = 0; n < 4; ++n) bRow[n] = (wc * 64 + n * 16 + l15) * 64;
  const int ch0 = (q ^ r7) * 8;
  const int ch1 = ((4 + q) ^ r7) * 8;

  f32x4 acc[4][4];
  #pragma unroll
  for (int m = 0; m < 4; ++m)
    #pragma unroll
    for (int n = 0; n < 4; ++n) { f32x4 z = {0.f,0.f,0.f,0.f}; acc[m][n] = z; }

  for (int kt = 0; kt < 16; ++kt) {
    const int ko = kt * 64;
    #pragma unroll
    for (int k = 0; k < 4; ++k) {
      gload_lds16(aBase + ko + aOff[k], aL + dOff[k]);
      gload_lds16(WcBf + ko + bOff[k], bL + dOff[k]);
    }
    __syncthreads();

    #pragma unroll
    for (int kk = 0; kk < 2; ++kk) {
      const int cho = kk ? ch1 : ch0;
      bf16x8 af[4], bv[4];
      #pragma unroll
      for (int m = 0; m < 4; ++m) af[m] = *(const bf16x8*)(aL + aRow[m] + cho);
      #pragma unroll
      for (int n = 0; n < 4; ++n) bv[n] = *(const bf16x8*)(bL + bRow[n] + cho);
      #pragma unroll
      for (int m = 0; m < 4; ++m)
        #pragma unroll
        for (int n = 0; n < 4; ++n)
          acc[m][n] = __builtin_amdgcn_mfma_f32_16x16x32_bf16(
              af[m], bv[n], acc[m][n], 0, 0, 0);
    }
    __syncthreads();
  }

  // epilogue: fold tanh(acc + wsum) . Wa over this block's 128-col slice
  #pragma unroll
  for (int m = 0; m < 4; ++m) {
    #pragma unroll
    for (int i = 0; i < 4; ++i) {
      const int rowl = wr * 64 + m * 16 + q * 4 + i;
      const int bb2 = rowl & 31;                // global row %32 == rowl%32
      float v = 0.f;
      #pragma unroll
      for (int n = 0; n < 4; ++n) {
        const int col = nblk * 128 + wc * 64 + n * 16 + l15;
        float x = acc[m][n][i] + wsum[bb2 * 1024 + col];
        v += fast_tanh(x) * Wa[col];
      }
      v += __shfl_xor(v, 1); v += __shfl_xor(v, 2);
      v += __shfl_xor(v, 4); v += __shfl_xor(v, 8);
      if (l15 == 0) atomicAdd(&scorep[rowl], v);   // 2 adds/row (wc=0,1), LDS
    }
  }
  __syncthreads();
  if (tid < 128) scoreP8[(rowBase + tid) * 8 + nblk] = scorep[tid];
}

// ---------------------------------------------------------------------------
// ctx (softmax fused): block (b, sc). Phase 1: sweep all 2048 s, reduce the
// 8 n-partials -> score -> exp; accumulate batch sum; stash own chunk's exp.
// Phase 2: out[b][:] += (exp/sum) * encBf[s,b,:] for s in chunk (atomicAdd,
// out pre-zeroed by memset).
// ---------------------------------------------------------------------------
__global__ __launch_bounds__(256) void ctx_kernel(
    const ushort_t* __restrict__ encBf, const float* __restrict__ scoreP8,
    float* __restrict__ out)
{
  const int b = blockIdx.x & 31, sc = blockIdx.x >> 5;
  const int t = threadIdx.x;
  __shared__ float eCh[128];
  __shared__ float red[256];

  const int chunk0 = sc * 128;
  float ssum = 0.f;
  for (int s = t; s < S_LEN; s += 256) {
    const float4* p = (const float4*)(scoreP8 + ((size_t)s * 32 + b) * 8);
    float4 u = p[0], v = p[1];
    float scv = ((u.x + u.y) + (u.z + u.w)) + ((v.x + v.y) + (v.z + v.w));
    float e = __expf(scv);                      // scores O(1): no max needed
    ssum += e;
    const int d = s - chunk0;
    if ((unsigned)d < 128u) eCh[d] = e;
  }
  red[t] = ssum;
  __syncthreads();
  #pragma unroll
  for (int o = 128; o > 0; o >>= 1) {
    if (t < o) red[t] += red[t + o];
    __syncthreads();
  }
  const float inv = 1.0f / red[0];

  float a0 = 0.f, a1 = 0.f, a2 = 0.f, a3 = 0.f;
  const int e0 = t * 4;
  #pragma unroll 4
  for (int si = 0; si < 128; ++si) {
    const int s = chunk0 + si;
    const float a = eCh[si];
    uint2 w = *(const uint2*)(encBf + ((size_t)s * 32 + b) * 1024 + e0);
    a0 += a * bflo(w.x); a1 += a * bfhi(w.x);
    a2 += a * bflo(w.y); a3 += a * bfhi(w.y);
  }
  float* op = out + b * 1024 + e0;
  atomicAdd(op + 0, a0 * inv); atomicAdd(op + 1, a1 * inv);
  atomicAdd(op + 2, a2 * inv); atomicAdd(op + 3, a3 * inv);
}

// ---------------------------------------------------------------------------
extern "C" void kernel_launch(void* const* d_in, const int* in_sizes, int n_in,
                              void* d_out, int out_size, void* d_ws, size_t ws_size,
                              hipStream_t stream) {
  const float* dec = (const float*)d_in[0];
  const float* enc = (const float*)d_in[1];
  const float* Wb  = (const float*)d_in[2];
  const float* Wc  = (const float*)d_in[3];
  const float* Wa  = (const float*)d_in[4];
  float* out = (float*)d_out;
  (void)in_sizes; (void)n_in; (void)ws_size;

  char* ws = (char*)d_ws;
  ushort_t* encBf   = (ushort_t*)ws;                               // 128 MB
  ushort_t* WcBf    = (ushort_t*)(ws + 134217728);                 // 2 MB
  float*    wsum    = (float*)(ws + 134217728 + 2097152);          // 128 KB
  float*    scoreP8 = (float*)(ws + 134217728 + 2097152 + 131072); // 2 MB

  hipMemsetAsync(out, 0, (size_t)out_size * sizeof(float), stream);
  prep_conv_kernel<<<2144, 256, 0, stream>>>(dec, Wb, Wc, enc, encBf, WcBf, wsum);
  score_kernel<<<4096, 256, 0, stream>>>(encBf, WcBf, wsum, Wa, scoreP8);
  ctx_kernel<<<512, 256, 0, stream>>>(encBf, scoreP8, out);
}